// Round 10
// baseline (620.516 us; speedup 1.0000x reference)
//
#include <hip/hip_runtime.h>

#define G_N 2048
#define T_N 256
#define C_N 8          // chunks
#define CH 32          // chunk length

// ws layout (floats): tables, flags, then scratch
#define A_OFF 0
#define B_OFF 262144
#define S_OFF 327680
#define FLAGS_OFF 344064ull      // [0..29] slot flags, [32+t] per-t table flags
#define WS_XT   344384ull
#define WS_YT   393536ull
#define WS_HT   436544ull
#define WS_PHI  502080ull
#define WS_MEND 510272ull
#define WS_NEED_BYTES (1034560ull * 4ull)

// fallback out-tail scratch (float offsets into d_out); out total = 37748736
#define OUT_TOTAL  37748736ull
#define EL         3072
#define MEND_OFF   37030912ull
#define HT_OFF     37555200ull
#define PHI_OFF    37620736ull
#define XT_OFF     37653504ull
#define YT_OFF     37702656ull
#define COVS4_BASE 1048576ull
#define FB_GUARD4  8209152ull    // (MEND_OFF - 4194304)/4

// power-DAG task tables (level-parallel; slots 0..15 = X^1..X^16, 16+(q-2)=Y^q)
__device__ const int g_dst[29] = {1, 2,3, 4,5,6,7, 8,9,10,11,12,13,14,15,
                                  16, 17,18, 19,20,21,22, 23,24,25,26,27,28,29};
__device__ const int g_sa[29]  = {0, 0,1, 0,1,2,3, 0,1,2,3,4,5,6,7,
                                  15, 15,16, 15,16,17,18, 15,16,17,18,19,20,21};
__device__ const int g_sb[29]  = {0, 1,1, 3,3,3,3, 7,7,7,7,7,7,7,7,
                                  15, 16,16, 18,18,18,18, 22,22,22,22,22,22,22};

// ---------------- float4 helpers ------------------------------------------
__device__ __forceinline__ float4 f4z() { return make_float4(0.f, 0.f, 0.f, 0.f); }
__device__ __forceinline__ float4 f4madd(float s, const float4 v, float4 a) {
    a.x += s * v.x; a.y += s * v.y; a.z += s * v.z; a.w += s * v.w; return a;
}
__device__ __forceinline__ float dot4(const float4 a, const float4 b) {
    return a.x * b.x + a.y * b.y + a.z * b.z + a.w * b.w;
}
__device__ __forceinline__ const float* slotc2(const float* xt, const float* yt, int s) {
    return (s < 16) ? (xt + (size_t)s * EL) : (yt + (size_t)(s - 16) * EL);
}
__device__ __forceinline__ float* slotw2(float* xt, float* yt, int s) {
    return (s < 16) ? (xt + (size_t)s * EL) : (yt + (size_t)(s - 16) * EL);
}

// ---------------- dataflow flags (agent-scope release/acquire) -------------
__device__ __forceinline__ void publish(int* flag) {
    __syncthreads();                 // all block stores drained (vmcnt before barrier)
    if (threadIdx.x == 0) {
        __threadfence();             // agent fence: L2 writeback
        __hip_atomic_store(flag, 1, __ATOMIC_RELEASE, __HIP_MEMORY_SCOPE_AGENT);
    }
}
__device__ __forceinline__ void waitflag(const int* flag) {
    if (threadIdx.x == 0) {
        while (__hip_atomic_load(flag, __ATOMIC_ACQUIRE, __HIP_MEMORY_SCOPE_AGENT) == 0)
            __builtin_amdgcn_s_sleep(8);
    }
    __syncthreads();
}

// ---------------- 8x8 inverse on wave 0 (shuffle GJ, SPD) ------------------
__device__ __forceinline__ void inv8_wave(int tid, const float (*A8)[12], float (*O8)[12]) {
    if (tid < 64) {
        int r = tid >> 3, c = tid & 7;
        float a = A8[r][c];
        float b = (r == c) ? 1.f : 0.f;
#pragma unroll
        for (int j = 0; j < 8; ++j) {
            float ajj = __shfl(a, j * 8 + j, 64);
            float pv = 1.0f / ajj;
            if (r == j) { a *= pv; b *= pv; }
            float ajc = __shfl(a, j * 8 + c, 64);
            float bjc = __shfl(b, j * 8 + c, 64);
            float arj = __shfl(a, r * 8 + j, 64);
            if (r != j) { a -= arj * ajc; b -= arj * bjc; }
        }
        O8[r][c] = b;
    }
}

// ---------------- in-register unpivoted 4x4 inverse ------------------------
__device__ __forceinline__ void inv4x4(float P[4][4]) {
#pragma unroll
    for (int j = 0; j < 4; ++j) {
        float pv = 1.0f / P[j][j];
        P[j][j] = pv;
#pragma unroll
        for (int c = 0; c < 4; ++c) if (c != j) P[j][c] *= pv;
#pragma unroll
        for (int r = 0; r < 4; ++r) if (r != j) {
            float f = P[r][j];
#pragma unroll
            for (int c = 0; c < 4; ++c) if (c != j) P[r][c] -= f * P[j][c];
            P[r][j] = -f * pv;
        }
    }
}

// ---------------- 256-thread 32x32 inverse (4x4 pivots + NS) ---------------
// pre: AugL=M, AugR=I, M saved in Msv (barrier'd).
// post: K in AugL, K^T in AugR, barrier'd.
__device__ void inv32_256(int tid, float (*Aug)[72], const float (*Msv)[36], float (*Tmp)[36]) {
    const int r = tid >> 3, c0 = (tid & 7) * 4;
#pragma unroll 1
    for (int jb = 0; jb < 8; ++jb) {
        const int p = 4 * jb;
        float P[4][4];
#pragma unroll
        for (int i = 0; i < 4; ++i)
#pragma unroll
            for (int q = 0; q < 4; ++q) P[i][q] = Aug[p + i][p + q];
        float L[4];
#pragma unroll
        for (int q = 0; q < 4; ++q) L[q] = Aug[r][p + q];
        float4 xl = *(float4*)&Aug[r][c0];
        float4 xr = *(float4*)&Aug[r][36 + c0];
        float4 ql[4], qr[4];
#pragma unroll
        for (int q = 0; q < 4; ++q) {
            ql[q] = *(float4*)&Aug[p + q][c0];
            qr[q] = *(float4*)&Aug[p + q][36 + c0];
        }
        __syncthreads();
        inv4x4(P);
        float4 nl, nr;
        if (r >= p && r < p + 4) {
            int i = r - p;
            nl = f4madd(P[i][3], ql[3], f4madd(P[i][2], ql[2], f4madd(P[i][1], ql[1], f4madd(P[i][0], ql[0], f4z()))));
            nr = f4madd(P[i][3], qr[3], f4madd(P[i][2], qr[2], f4madd(P[i][1], qr[1], f4madd(P[i][0], qr[0], f4z()))));
        } else {
            float LP[4];
#pragma unroll
            for (int q = 0; q < 4; ++q)
                LP[q] = L[0] * P[0][q] + L[1] * P[1][q] + L[2] * P[2][q] + L[3] * P[3][q];
            nl = xl; nr = xr;
#pragma unroll
            for (int q = 0; q < 4; ++q) { nl = f4madd(-LP[q], ql[q], nl); nr = f4madd(-LP[q], qr[q], nr); }
        }
        *(float4*)&Aug[r][c0] = nl;
        *(float4*)&Aug[r][36 + c0] = nr;
        __syncthreads();
    }
    float4 acc = f4z();
#pragma unroll
    for (int k = 0; k < 32; ++k) acc = f4madd(Msv[r][k], *(const float4*)&Aug[k][36 + c0], acc);
    *(float4*)&Tmp[r][c0] = acc;
    __syncthreads();
    float4 k4 = *(const float4*)&Aug[r][36 + c0];
    float4 a2 = f4z();
#pragma unroll
    for (int k = 0; k < 32; ++k) a2 = f4madd(Aug[r][36 + k], *(const float4*)&Tmp[k][c0], a2);
    float4 kv = make_float4(2.f * k4.x - a2.x, 2.f * k4.y - a2.y, 2.f * k4.z - a2.z, 2.f * k4.w - a2.w);
    __syncthreads();
    *(float4*)&Aug[r][c0] = kv;
    Aug[c0 + 0][36 + r] = kv.x;
    Aug[c0 + 1][36 + r] = kv.y;
    Aug[c0 + 2][36 + r] = kv.z;
    Aug[c0 + 3][36 + r] = kv.w;
    __syncthreads();
}

// ---------------- matmul fragments (row-broadcast, conflict-free) ----------
__device__ __forceinline__ float4 mm4(const float (*A)[36], const float (*B)[36], int r, int c0) {
    float4 acc = f4z();
#pragma unroll
    for (int k = 0; k < 32; ++k) acc = f4madd(A[r][k], *(const float4*)&B[k][c0], acc);
    return acc;
}
__device__ __forceinline__ float4 mm4K(const float (*A)[36], const float (*Aug)[72], int r, int c0) {
    float4 acc = f4z();
#pragma unroll
    for (int k = 0; k < 32; ++k) acc = f4madd(A[r][k], *(const float4*)&Aug[k][c0], acc);
    return acc;
}
__device__ __forceinline__ float4 mmK4(const float (*Aug)[72], const float (*B)[36], int r, int c0) {
    float4 acc = f4z();
#pragma unroll
    for (int k = 0; k < 32; ++k) acc = f4madd(Aug[r][k], *(const float4*)&B[k][c0], acc);
    return acc;
}
__device__ __forceinline__ float4 mm4R(const float (*A)[36], const float (*Aug)[72], int r, int c0) {
    float4 acc = f4z();
#pragma unroll
    for (int k = 0; k < 32; ++k) acc = f4madd(A[r][k], *(const float4*)&Aug[k][36 + c0], acc);
    return acc;
}

// ---------------- compose (256 threads, conflict-free) ---------------------
// result: E''->Msv, F''->T5, G''->T3. Destroys Ea (becomes Fa^T) and Gb
// (becomes Fb^T). Ends barrier'd.
__device__ void compose256(int tid,
    float (*Ea)[36], const float (*Fa)[36], const float (*Ga)[36],
    const float (*Eb)[36], const float (*Fb)[36], float (*Gb)[36],
    float (*Msv)[36], float (*T1)[36], float (*T3)[36], float (*T4)[36], float (*T5)[36],
    float (*Aug)[72])
{
    const int r = tid >> 3, c0 = (tid & 7) * 4;
    {
        float4 m4 = mm4(Gb, Ea, r, c0);
        m4.x += (r == c0 + 0) ? 1.f : 0.f; m4.y += (r == c0 + 1) ? 1.f : 0.f;
        m4.z += (r == c0 + 2) ? 1.f : 0.f; m4.w += (r == c0 + 3) ? 1.f : 0.f;
        float4 id4 = make_float4((r == c0 + 0) ? 1.f : 0.f, (r == c0 + 1) ? 1.f : 0.f,
                                 (r == c0 + 2) ? 1.f : 0.f, (r == c0 + 3) ? 1.f : 0.f);
        *(float4*)&Aug[r][c0] = m4;
        *(float4*)&Msv[r][c0] = m4;
        *(float4*)&Aug[r][36 + c0] = id4;
    }
    __syncthreads();
    inv32_256(tid, Aug, Msv, T4);
    {
        float4 t1 = mm4K(Ea, Aug, r, c0);
        float4 t4 = mmK4(Aug, Gb, r, c0);
        float4 t3 = mm4R(Fb, Aug, r, c0);
        *(float4*)&T1[r][c0] = t1; *(float4*)&T4[r][c0] = t4; *(float4*)&T3[r][c0] = t3;
    }
    __syncthreads();
    {
        float4 bt = mm4(Fb, T1, r, c0);
        float4 t5 = mm4(T3, Fa, r, c0);
        float4 fav = *(const float4*)&Fa[r][c0];
        float4 fbv = *(const float4*)&Fb[r][c0];
        *(float4*)&Aug[r][36 + c0] = bt; *(float4*)&T5[r][c0] = t5;
        Ea[c0 + 0][r] = fav.x; Ea[c0 + 1][r] = fav.y;
        Ea[c0 + 2][r] = fav.z; Ea[c0 + 3][r] = fav.w;
        Gb[c0 + 0][r] = fbv.x; Gb[c0 + 1][r] = fbv.y;
        Gb[c0 + 2][r] = fbv.z; Gb[c0 + 3][r] = fbv.w;
    }
    __syncthreads();
    {
        float4 ev = *(const float4*)&Eb[r][c0];
        float4 acc = f4z();
#pragma unroll
        for (int k = 0; k < 32; ++k) acc = f4madd(Aug[r][36 + k], *(const float4*)&Gb[k][c0], acc);
        ev.x += acc.x; ev.y += acc.y; ev.z += acc.z; ev.w += acc.w;
        float4 t1n = mm4(Ea, T4, r, c0);
        *(float4*)&Msv[r][c0] = ev;
        *(float4*)&T1[r][c0] = t1n;
    }
    __syncthreads();
    {
        float4 g4 = mm4(T1, Fa, r, c0);
        float4 ga = *(const float4*)&Ga[r][c0];
        g4.x += ga.x; g4.y += ga.y; g4.z += ga.z; g4.w += ga.w;
        *(float4*)&T3[r][c0] = g4;
    }
    __syncthreads();
}

__device__ __forceinline__ void load_el256(const float* g, int tid,
    float (*E)[36], float (*F)[36], float (*G)[36]) {
    const int r = tid >> 3, c0 = (tid & 7) * 4;
    *(float4*)&E[r][c0] = *(const float4*)&g[tid * 4];
    *(float4*)&F[r][c0] = *(const float4*)&g[1024 + tid * 4];
    *(float4*)&G[r][c0] = *(const float4*)&g[2048 + tid * 4];
}

// ---------------------------------------------------------------------------
// PFLOW (single dispatch, 256 blocks x 256 thr, flag-based dataflow):
// init (b0) -> 29 scan tasks (b1..29) -> per-t tables (all b) -> tpre (b0..7)
// ---------------------------------------------------------------------------
__global__ __launch_bounds__(256) void kf_pflow(
    const float* __restrict__ Fg, const float* __restrict__ Hg,
    const float* __restrict__ Qg, const float* __restrict__ Rg,
    const float* __restrict__ P0, float* __restrict__ ws,
    float* __restrict__ xt, float* __restrict__ yt,
    float* __restrict__ ht, float* __restrict__ phi,
    int* __restrict__ flags)
{
    __shared__ float Ea[32][36], Fa[32][36], Ga[32][36];
    __shared__ float Eb[32][36], Fb[32][36], Gb[32][36];
    __shared__ float Msv[32][36], T1[32][36], T3[32][36], T4[32][36], T5[32][36];
    __shared__ float Aug[32][72];
    __shared__ float Ss[8][12], Rs[8][12], Sis[8][12];

    const int tid = threadIdx.x, b = blockIdx.x;
    const int r = tid >> 3, c0 = (tid & 7) * 4;
    int* sflag = flags;          // 30 slot flags
    int* fflag = flags + 32;     // 256 per-t table flags

    // ---------- INIT: block 0 builds base element {Q, F, H^T R^-1 H} ----------
    if (b == 0) {
        float (*Hs_)[36]  = (float (*)[36])Ga;
        float (*RHs_)[36] = (float (*)[36])T4;
        if (tid < 64) *(float4*)&Hs_[tid >> 3][(tid & 7) * 4] = *(const float4*)&Hg[tid * 4];
        if (tid < 64) Rs[tid >> 3][tid & 7] = Rg[tid];
        __syncthreads();
        inv8_wave(tid, Rs, Sis);
        __syncthreads();
        {
            int m = tid >> 5, jj = tid & 31;
            float s = 0.f;
#pragma unroll
            for (int n = 0; n < 8; ++n) s += Sis[m][n] * Hs_[n][jj];
            RHs_[m][jj] = s;
        }
        __syncthreads();
        {
            float4 acc = f4z();
#pragma unroll
            for (int m = 0; m < 8; ++m) acc = f4madd(Hs_[m][r], *(const float4*)&RHs_[m][c0], acc);
            *(float4*)&xt[2048 + tid * 4] = acc;
        }
        *(float4*)&xt[tid * 4]        = *(const float4*)&Qg[tid * 4];
        *(float4*)&xt[1024 + tid * 4] = *(const float4*)&Fg[tid * 4];
        publish(&sflag[0]);
    }

    // ---------- SCAN TASKS: blocks 1..29 ----------
    if (b >= 1 && b <= 29) {
        const int ti = b - 1;
        waitflag(&sflag[g_sa[ti]]);
        waitflag(&sflag[g_sb[ti]]);
        load_el256(slotc2(xt, yt, g_sa[ti]), tid, Ea, Fa, Ga);
        load_el256(slotc2(xt, yt, g_sb[ti]), tid, Eb, Fb, Gb);
        __syncthreads();
        compose256(tid, Ea, Fa, Ga, Eb, Fb, Gb, Msv, T1, T3, T4, T5, Aug);
        float* pd = slotw2(xt, yt, g_dst[ti]);
        float4 e, f, g2;
        e.x = 0.5f * (Msv[r][c0 + 0] + Msv[c0 + 0][r]); e.y = 0.5f * (Msv[r][c0 + 1] + Msv[c0 + 1][r]);
        e.z = 0.5f * (Msv[r][c0 + 2] + Msv[c0 + 2][r]); e.w = 0.5f * (Msv[r][c0 + 3] + Msv[c0 + 3][r]);
        f = *(const float4*)&T5[r][c0];
        g2.x = 0.5f * (T3[r][c0 + 0] + T3[c0 + 0][r]); g2.y = 0.5f * (T3[r][c0 + 1] + T3[c0 + 1][r]);
        g2.z = 0.5f * (T3[r][c0 + 2] + T3[c0 + 2][r]); g2.w = 0.5f * (T3[r][c0 + 3] + T3[c0 + 3][r]);
        *(float4*)&pd[tid * 4] = e;
        *(float4*)&pd[1024 + tid * 4] = f;
        *(float4*)&pd[2048 + tid * 4] = g2;
        publish(&sflag[g_dst[ti]]);
    }

    // ---------- FINAL: tables for t = b ----------
    {
        const int t = b;
        if (t == 0) {
            *(float4*)&Eb[r][c0] = *(const float4*)&P0[tid * 4];
            __syncthreads();
        } else {
            const int i = t - 1, s = (i & 15) + 1, q = i >> 4;
            const int slot_b = (q == 1) ? 15 : 16 + q - 2;
            waitflag(&sflag[s - 1]);
            if (q >= 1) waitflag(&sflag[slot_b]);
            if (q == 0) {
                load_el256(xt + (size_t)(s - 1) * EL, tid, Msv, T5, T3);
                __syncthreads();
            } else {
                load_el256(xt + (size_t)(s - 1) * EL, tid, Ea, Fa, Ga);
                load_el256(slotc2(xt, yt, slot_b), tid, Eb, Fb, Gb);
                __syncthreads();
                compose256(tid, Ea, Fa, Ga, Eb, Fb, Gb, Msv, T1, T3, T4, T5, Aug);
            }
            // P_t = E + F*(P0*(I+G*P0)^-1)*F^T   (E=Msv, F=T5, G=T3)
            *(float4*)&Ea[r][c0] = *(const float4*)&P0[tid * 4];
            __syncthreads();
            {
                float4 m4 = mm4(T3, Ea, r, c0);
                m4.x += (r == c0 + 0) ? 1.f : 0.f; m4.y += (r == c0 + 1) ? 1.f : 0.f;
                m4.z += (r == c0 + 2) ? 1.f : 0.f; m4.w += (r == c0 + 3) ? 1.f : 0.f;
                float4 id4 = make_float4((r == c0 + 0) ? 1.f : 0.f, (r == c0 + 1) ? 1.f : 0.f,
                                         (r == c0 + 2) ? 1.f : 0.f, (r == c0 + 3) ? 1.f : 0.f);
                *(float4*)&Aug[r][c0] = m4; *(float4*)&T4[r][c0] = m4;
                *(float4*)&Aug[r][36 + c0] = id4;
            }
            __syncthreads();
            inv32_256(tid, Aug, T4, T1);
            *(float4*)&T1[r][c0] = mm4K(Ea, Aug, r, c0);      // P0*K
            __syncthreads();
            *(float4*)&T4[r][c0] = mm4(T5, T1, r, c0);        // F*(P0K)
            __syncthreads();
            {   // Ga(temp) = Msv + T4*T5^T
                float4 ev = *(const float4*)&Msv[r][c0];
                float s0 = 0, s1 = 0, s2 = 0, s3 = 0;
#pragma unroll
                for (int k = 0; k < 32; ++k) {
                    float av = T4[r][k];
                    s0 += av * T5[c0 + 0][k]; s1 += av * T5[c0 + 1][k];
                    s2 += av * T5[c0 + 2][k]; s3 += av * T5[c0 + 3][k];
                }
                ev.x += s0; ev.y += s1; ev.z += s2; ev.w += s3;
                *(float4*)&Ga[r][c0] = ev;
            }
            __syncthreads();
            {   // Pm symmetrized -> Eb
                float4 e;
                e.x = 0.5f * (Ga[r][c0 + 0] + Ga[c0 + 0][r]); e.y = 0.5f * (Ga[r][c0 + 1] + Ga[c0 + 1][r]);
                e.z = 0.5f * (Ga[r][c0 + 2] + Ga[c0 + 2][r]); e.w = 0.5f * (Ga[r][c0 + 3] + Ga[c0 + 3][r]);
                *(float4*)&Eb[r][c0] = e;
            }
            __syncthreads();
        }

        // tables from Pm = Eb (LDS aliases: Hs->Ga, HPs->T4, Wms->T1, Ums->Aug)
        float (*Hs_)[36]  = (float (*)[36])Ga;
        float (*HPs_)[36] = T4;
        float (*Wms_)[36] = T1;
        float (*Ums_)[36] = (float (*)[36])&Aug[0][0];
        *(float4*)&Fa[r][c0] = *(const float4*)&Fg[tid * 4];
        if (tid < 64) *(float4*)&Hs_[tid >> 3][(tid & 7) * 4] = *(const float4*)&Hg[tid * 4];
        if (tid < 64) Rs[tid >> 3][tid & 7] = Rg[tid];
        __syncthreads();
        {
            int m = tid >> 5, k2 = tid & 31;
            float a = 0.f;
#pragma unroll
            for (int j = 0; j < 32; ++j) a += Hs_[m][j] * Eb[j][k2];
            HPs_[m][k2] = a;
        }
        __syncthreads();
        {
            int m = tid >> 5, jj = tid & 31;
            float wv = 0.f;
#pragma unroll
            for (int k = 0; k < 32; ++k) wv += HPs_[m][k] * Fa[jj][k];
            Wms_[m][jj] = wv;
            if (tid < 64) {
                int mm = tid >> 3, n = tid & 7;
                float sv = Rs[mm][n];
#pragma unroll
                for (int k = 0; k < 32; ++k) sv += HPs_[mm][k] * Hs_[n][k];
                Ss[mm][n] = sv;
                ws[S_OFF + (size_t)t * 64 + tid] = sv;
            }
        }
        __syncthreads();
        inv8_wave(tid, Ss, Sis);
        __syncthreads();
        {
            int m = tid >> 5, s2 = tid & 31;
            float u = 0.f;
#pragma unroll
            for (int n = 0; n < 8; ++n) u += Sis[m][n] * Wms_[n][s2];
            Ums_[m][s2] = u;
            ws[B_OFF + (size_t)t * 256 + s2 * 8 + m] = u;
        }
        __syncthreads();
        {
            float4 a4 = *(const float4*)&Fa[r][c0];
#pragma unroll
            for (int m = 0; m < 8; ++m) {
                float um = Ums_[m][r];
                a4 = f4madd(-um, *(const float4*)&Hs_[m][c0], a4);
            }
            ((float4*)(ws + A_OFF))[(size_t)t * 256 + tid] = a4;
        }
        publish(&fflag[t]);
    }

    // ---------- TPRE: blocks 0..7, chunk transition products ----------
    if (b < 8) {
        const int t0 = CH * b;
        if (tid < 32) {
            while (__hip_atomic_load(&fflag[t0 + tid], __ATOMIC_ACQUIRE,
                                     __HIP_MEMORY_SCOPE_AGENT) == 0)
                __builtin_amdgcn_s_sleep(8);
        }
        __syncthreads();

        float (*Ta_)[36] = Msv;
        float (*Tb_)[36] = T1;
        float (*As_)[36] = T3;
        float (*Hs_)[36] = (float (*)[36])Ga;     // H still resident from FINAL
        const float4* A4 = (const float4*)(ws + A_OFF);
        {
            float4 id4 = make_float4((r == c0 + 0) ? 1.f : 0.f, (r == c0 + 1) ? 1.f : 0.f,
                                     (r == c0 + 2) ? 1.f : 0.f, (r == c0 + 3) ? 1.f : 0.f);
            *(float4*)&Ta_[r][c0] = id4;
        }
        ht[(size_t)t0 * 256 + tid] = Hg[tid];
        *(float4*)&As_[r][c0] = A4[(size_t)t0 * 256 + tid];
        __syncthreads();
        float (*cur)[36] = Ta_, (*nxt)[36] = Tb_;
        for (int k = 1; k <= CH; ++k) {
            *(float4*)&nxt[r][c0] = mm4(As_, cur, r, c0);
            __syncthreads();
            if (k < CH) {
                int m = tid >> 5, s2 = tid & 31;
                float h = 0.f;
#pragma unroll
                for (int j = 0; j < 32; ++j) h += Hs_[m][j] * nxt[j][s2];
                ht[(size_t)(t0 + k) * 256 + tid] = h;
                *(float4*)&As_[r][c0] = A4[(size_t)(t0 + k) * 256 + tid];
            } else {
                ((float4*)phi)[(size_t)b * 256 + tid] = *(const float4*)&nxt[r][c0];
            }
            __syncthreads();
            float (*tmp)[36] = cur; cur = nxt; nxt = tmp;
        }
    }
}

// ---------------------------------------------------------------------------
// M1: one-wave blocks; A_t/B_t/H in registers, m in LDS; zero barriers.
// ---------------------------------------------------------------------------
__global__ __launch_bounds__(64) void kf_m1(
    const float* __restrict__ obs, const float* __restrict__ Hg,
    const float* __restrict__ ws, float* __restrict__ mend,
    float* __restrict__ means)
{
    __shared__ float mc[8][36];
    __shared__ float us[8][12];
    const int lane = threadIdx.x;
    const int rA = lane >> 1, hA = lane & 1;
    const int rH = lane >> 3, cH = lane & 7;
    const int cc = blockIdx.x >> 8;
    const int gb = (blockIdx.x & 255) * 8;
    const int t0 = cc * CH;
    const float4* A4 = (const float4*)(ws + A_OFF);
    const float4* B4 = (const float4*)(ws + B_OFF);
    const float4* obs4 = (const float4*)obs;

    const float4 h4 = *(const float4*)&Hg[rH * 32 + cH * 4];

    {
        float* mf = &mc[0][0];
        for (int i = lane; i < 8 * 36; i += 64) mf[i] = 0.f;
    }

    float4 an0 = A4[(size_t)t0 * 256 + lane * 4 + 0];
    float4 an1 = A4[(size_t)t0 * 256 + lane * 4 + 1];
    float4 an2 = A4[(size_t)t0 * 256 + lane * 4 + 2];
    float4 an3 = A4[(size_t)t0 * 256 + lane * 4 + 3];
    float4 bn  = B4[(size_t)t0 * 64 + lane];
    float4 un = f4z();
    if (lane < 16) un = obs4[((size_t)(gb + (lane >> 1)) * 256 + t0) * 2 + (lane & 1)];

    for (int k = 0; k < CH; ++k) {
        const int t = t0 + k;
        const float4 a0 = an0, a1 = an1, a2 = an2, a3 = an3, bb = bn;
        if (lane < 16) *(float4*)&us[lane >> 1][(lane & 1) * 4] = un;
        if (k < CH - 1) {
            an0 = A4[(size_t)(t + 1) * 256 + lane * 4 + 0];
            an1 = A4[(size_t)(t + 1) * 256 + lane * 4 + 1];
            an2 = A4[(size_t)(t + 1) * 256 + lane * 4 + 2];
            an3 = A4[(size_t)(t + 1) * 256 + lane * 4 + 3];
            bn  = B4[(size_t)(t + 1) * 64 + lane];
            if (lane < 16) un = obs4[((size_t)(gb + (lane >> 1)) * 256 + t + 1) * 2 + (lane & 1)];
        }
#pragma unroll 1
        for (int gl = 0; gl < 8; ++gl) {
            float4 mh = *(const float4*)&mc[gl][cH * 4];
            float hp = dot4(h4, mh);
            hp += __shfl_xor(hp, 1);
            hp += __shfl_xor(hp, 2);
            hp += __shfl_xor(hp, 4);
            float4 m0v = *(const float4*)&mc[gl][hA * 16 + 0];
            float4 m1v = *(const float4*)&mc[gl][hA * 16 + 4];
            float4 m2v = *(const float4*)&mc[gl][hA * 16 + 8];
            float4 m3v = *(const float4*)&mc[gl][hA * 16 + 12];
            float d = dot4(a0, m0v) + dot4(a1, m1v) + dot4(a2, m2v) + dot4(a3, m3v);
            float4 u4 = *(const float4*)&us[gl][hA * 4];
            d += dot4(bb, u4);
            d += __shfl_xor(d, 1);
            if ((lane & 7) == 0) means[((size_t)(gb + gl) * 256 + t) * 8 + rH] = hp;
            if (hA == 0) mc[gl][rA] = d;
        }
    }
#pragma unroll 1
    for (int gl = 0; gl < 8; ++gl)
        if (hA == 0) mend[((size_t)(gb + gl) * 8 + cc) * 32 + rA] = mc[gl][rA];
}

// ---------------------------------------------------------------------------
// M2: one g per block — chunk prefix (wave 0) + means correction + covs
// ---------------------------------------------------------------------------
__global__ __launch_bounds__(256) void kf_m2(
    const float* __restrict__ m0, const float* __restrict__ ws,
    const float* __restrict__ ht, const float* __restrict__ phi,
    const float* __restrict__ mend, float* __restrict__ out,
    unsigned long long guard4)
{
    __shared__ float mst[256];
    const int tid = threadIdx.x;
    const size_t g = blockIdx.x;

    if (tid < 32) {
        const int s = tid;
        const float4* PHI4 = (const float4*)phi;
        float msr = m0[g * 32 + s];
        for (int cc = 0; cc < C_N; ++cc) {
            mst[cc * 32 + s] = msr;
            if (cc < C_N - 1) {
                float nv = mend[(g * 8 + cc) * 32 + s];
#pragma unroll
                for (int q4 = 0; q4 < 8; ++q4) {
                    float4 p = PHI4[cc * 256 + s * 8 + q4];
                    nv += p.x * __shfl(msr, 4 * q4 + 0, 32) + p.y * __shfl(msr, 4 * q4 + 1, 32)
                        + p.z * __shfl(msr, 4 * q4 + 2, 32) + p.w * __shfl(msr, 4 * q4 + 3, 32);
                }
                msr = nv;
            }
        }
    }
    __syncthreads();

    const float4* HT4 = (const float4*)ht;
#pragma unroll
    for (int j = 0; j < 8; ++j) {
        const int idx = tid + 256 * j;            // = t*8 + m
        const int t = idx >> 3, m = idx & 7, cc = t >> 5;
        float corr = 0.f;
#pragma unroll
        for (int q4 = 0; q4 < 8; ++q4) {
            float4 h = HT4[(size_t)t * 64 + m * 8 + q4];
            float4 mm = *(const float4*)&mst[cc * 32 + 4 * q4];
            corr += dot4(h, mm);
        }
        out[g * 2048 + idx] += corr;
    }

    const float4* S4 = (const float4*)(ws + S_OFF);
    float4* covs4 = (float4*)out + COVS4_BASE;
#pragma unroll
    for (int k = 0; k < 16; ++k) {
        const size_t i = (size_t)tid + 256 * k;
        const size_t rel = g * 4096 + i;
        if (rel < guard4) covs4[rel] = S4[i];
    }
}

// ---------------------------------------------------------------------------
// CLEAN (fallback only): fill the covs span that was used as scratch
// ---------------------------------------------------------------------------
__global__ void kf_clean(const float* __restrict__ ws, float* __restrict__ out)
{
    float4* out4 = (float4*)out;
    const float4* S4 = (const float4*)(ws + S_OFF);
    const size_t start = COVS4_BASE + FB_GUARD4;
    const size_t end = OUT_TOTAL / 4;
    size_t i = start + (size_t)blockIdx.x * blockDim.x + threadIdx.x;
    const size_t stride = (size_t)gridDim.x * blockDim.x;
    for (; i < end; i += stride) {
        size_t rel = i - COVS4_BASE;
        out4[i] = S4[rel & 4095];
    }
}

extern "C" void kernel_launch(void* const* d_in, const int* in_sizes, int n_in,
                              void* d_out, int out_size, void* d_ws, size_t ws_size,
                              hipStream_t stream) {
    const float* obs = (const float*)d_in[0];
    const float* F   = (const float*)d_in[1];
    const float* H   = (const float*)d_in[2];
    const float* Q   = (const float*)d_in[3];
    const float* R   = (const float*)d_in[4];
    const float* m0  = (const float*)d_in[5];
    const float* P0  = (const float*)d_in[6];
    float* out = (float*)d_out;
    float* ws  = (float*)d_ws;

    const bool use_ws = (ws_size >= WS_NEED_BYTES);
    float *xt, *yt, *ht, *phi, *mend;
    unsigned long long guard4;
    if (use_ws) {
        xt = ws + WS_XT; yt = ws + WS_YT; ht = ws + WS_HT;
        phi = ws + WS_PHI; mend = ws + WS_MEND;
        guard4 = 4096ull * (unsigned long long)G_N;   // no clipping
    } else {
        xt = out + XT_OFF; yt = out + YT_OFF; ht = out + HT_OFF;
        phi = out + PHI_OFF; mend = out + MEND_OFF;
        guard4 = FB_GUARD4;
    }
    int* flags = (int*)(ws + FLAGS_OFF);

    hipMemsetAsync((void*)flags, 0, 320 * sizeof(int), stream);
    kf_pflow<<<256, 256, 0, stream>>>(F, H, Q, R, P0, ws, xt, yt, ht, phi, flags);
    kf_m1<<<2048, 64, 0, stream>>>(obs, H, ws, mend, out);
    kf_m2<<<2048, 256, 0, stream>>>(m0, ws, ht, phi, mend, out, guard4);
    if (!use_ws) kf_clean<<<512, 256, 0, stream>>>(ws, out);
}

// Round 11
// 469.054 us; speedup vs baseline: 1.3229x; 1.3229x over previous
//
#include <hip/hip_runtime.h>

#define G_N 2048
#define T_N 256
#define C_N 8          // chunks
#define CH 32          // chunk length

// ws layout (floats): tables then scratch
#define A_OFF 0
#define B_OFF 262144
#define S_OFF 327680
#define WS_XT   344384ull
#define WS_YT   393536ull
#define WS_HT   436544ull
#define WS_PHI  502080ull
#define WS_MEND 510272ull
#define WS_NEED_BYTES (1034560ull * 4ull)

// fallback out-tail scratch (float offsets into d_out); out total = 37748736
#define OUT_TOTAL  37748736ull
#define EL         3072
#define MEND_OFF   37030912ull
#define HT_OFF     37555200ull
#define PHI_OFF    37620736ull
#define XT_OFF     37653504ull
#define YT_OFF     37702656ull
#define COVS4_BASE 1048576ull
#define FB_GUARD4  8209152ull    // (MEND_OFF - 4194304)/4

// ---------------- float4 helpers ------------------------------------------
__device__ __forceinline__ float4 f4z() { return make_float4(0.f, 0.f, 0.f, 0.f); }
__device__ __forceinline__ float4 f4madd(float s, const float4 v, float4 a) {
    a.x += s * v.x; a.y += s * v.y; a.z += s * v.z; a.w += s * v.w; return a;
}
__device__ __forceinline__ float dot4(const float4 a, const float4 b) {
    return a.x * b.x + a.y * b.y + a.z * b.z + a.w * b.w;
}

// ---------------- 8x8 inverse on wave 0 (shuffle GJ, SPD) ------------------
__device__ __forceinline__ void inv8_wave(int tid, const float (*A8)[12], float (*O8)[12]) {
    if (tid < 64) {
        int r = tid >> 3, c = tid & 7;
        float a = A8[r][c];
        float b = (r == c) ? 1.f : 0.f;
#pragma unroll
        for (int j = 0; j < 8; ++j) {
            float ajj = __shfl(a, j * 8 + j, 64);
            float pv = 1.0f / ajj;
            if (r == j) { a *= pv; b *= pv; }
            float ajc = __shfl(a, j * 8 + c, 64);
            float bjc = __shfl(b, j * 8 + c, 64);
            float arj = __shfl(a, r * 8 + j, 64);
            if (r != j) { a -= arj * ajc; b -= arj * bjc; }
        }
        O8[r][c] = b;
    }
}

// ---------------- in-register unpivoted 4x4 inverse ------------------------
__device__ __forceinline__ void inv4x4(float P[4][4]) {
#pragma unroll
    for (int j = 0; j < 4; ++j) {
        float pv = 1.0f / P[j][j];
        P[j][j] = pv;
#pragma unroll
        for (int c = 0; c < 4; ++c) if (c != j) P[j][c] *= pv;
#pragma unroll
        for (int r = 0; r < 4; ++r) if (r != j) {
            float f = P[r][j];
#pragma unroll
            for (int c = 0; c < 4; ++c) if (c != j) P[r][c] -= f * P[j][c];
            P[r][j] = -f * pv;
        }
    }
}

// ---------------- 256-thread 32x32 inverse (4x4 pivots + NS) ---------------
// pre: AugL=M, AugR=I, M saved in Msv (barrier'd).
// post: K in AugL, K^T in AugR, barrier'd.
__device__ void inv32_256(int tid, float (*Aug)[72], const float (*Msv)[36], float (*Tmp)[36]) {
    const int r = tid >> 3, c0 = (tid & 7) * 4;
#pragma unroll 1
    for (int jb = 0; jb < 8; ++jb) {
        const int p = 4 * jb;
        float P[4][4];
#pragma unroll
        for (int i = 0; i < 4; ++i)
#pragma unroll
            for (int q = 0; q < 4; ++q) P[i][q] = Aug[p + i][p + q];
        float L[4];
#pragma unroll
        for (int q = 0; q < 4; ++q) L[q] = Aug[r][p + q];
        float4 xl = *(float4*)&Aug[r][c0];
        float4 xr = *(float4*)&Aug[r][36 + c0];
        float4 ql[4], qr[4];
#pragma unroll
        for (int q = 0; q < 4; ++q) {
            ql[q] = *(float4*)&Aug[p + q][c0];
            qr[q] = *(float4*)&Aug[p + q][36 + c0];
        }
        __syncthreads();
        inv4x4(P);
        float4 nl, nr;
        if (r >= p && r < p + 4) {
            int i = r - p;
            nl = f4madd(P[i][3], ql[3], f4madd(P[i][2], ql[2], f4madd(P[i][1], ql[1], f4madd(P[i][0], ql[0], f4z()))));
            nr = f4madd(P[i][3], qr[3], f4madd(P[i][2], qr[2], f4madd(P[i][1], qr[1], f4madd(P[i][0], qr[0], f4z()))));
        } else {
            float LP[4];
#pragma unroll
            for (int q = 0; q < 4; ++q)
                LP[q] = L[0] * P[0][q] + L[1] * P[1][q] + L[2] * P[2][q] + L[3] * P[3][q];
            nl = xl; nr = xr;
#pragma unroll
            for (int q = 0; q < 4; ++q) { nl = f4madd(-LP[q], ql[q], nl); nr = f4madd(-LP[q], qr[q], nr); }
        }
        *(float4*)&Aug[r][c0] = nl;
        *(float4*)&Aug[r][36 + c0] = nr;
        __syncthreads();
    }
    float4 acc = f4z();
#pragma unroll
    for (int k = 0; k < 32; ++k) acc = f4madd(Msv[r][k], *(const float4*)&Aug[k][36 + c0], acc);
    *(float4*)&Tmp[r][c0] = acc;
    __syncthreads();
    float4 k4 = *(const float4*)&Aug[r][36 + c0];
    float4 a2 = f4z();
#pragma unroll
    for (int k = 0; k < 32; ++k) a2 = f4madd(Aug[r][36 + k], *(const float4*)&Tmp[k][c0], a2);
    float4 kv = make_float4(2.f * k4.x - a2.x, 2.f * k4.y - a2.y, 2.f * k4.z - a2.z, 2.f * k4.w - a2.w);
    __syncthreads();
    *(float4*)&Aug[r][c0] = kv;
    Aug[c0 + 0][36 + r] = kv.x;
    Aug[c0 + 1][36 + r] = kv.y;
    Aug[c0 + 2][36 + r] = kv.z;
    Aug[c0 + 3][36 + r] = kv.w;
    __syncthreads();
}

// ---------------- matmul fragments (row-broadcast, conflict-free) ----------
__device__ __forceinline__ float4 mm4(const float (*A)[36], const float (*B)[36], int r, int c0) {
    float4 acc = f4z();
#pragma unroll
    for (int k = 0; k < 32; ++k) acc = f4madd(A[r][k], *(const float4*)&B[k][c0], acc);
    return acc;
}
__device__ __forceinline__ float4 mm4K(const float (*A)[36], const float (*Aug)[72], int r, int c0) {
    float4 acc = f4z();
#pragma unroll
    for (int k = 0; k < 32; ++k) acc = f4madd(A[r][k], *(const float4*)&Aug[k][c0], acc);
    return acc;
}
__device__ __forceinline__ float4 mmK4(const float (*Aug)[72], const float (*B)[36], int r, int c0) {
    float4 acc = f4z();
#pragma unroll
    for (int k = 0; k < 32; ++k) acc = f4madd(Aug[r][k], *(const float4*)&B[k][c0], acc);
    return acc;
}
__device__ __forceinline__ float4 mm4R(const float (*A)[36], const float (*Aug)[72], int r, int c0) {
    float4 acc = f4z();
#pragma unroll
    for (int k = 0; k < 32; ++k) acc = f4madd(A[r][k], *(const float4*)&Aug[k][36 + c0], acc);
    return acc;
}

// ---------------- compose (256 threads, conflict-free) ---------------------
// result: E''->Msv, F''->T5, G''->T3. Destroys Ea (becomes Fa^T) and Gb
// (becomes Fb^T). Ends barrier'd.
__device__ void compose256(int tid,
    float (*Ea)[36], const float (*Fa)[36], const float (*Ga)[36],
    const float (*Eb)[36], const float (*Fb)[36], float (*Gb)[36],
    float (*Msv)[36], float (*T1)[36], float (*T3)[36], float (*T4)[36], float (*T5)[36],
    float (*Aug)[72])
{
    const int r = tid >> 3, c0 = (tid & 7) * 4;
    {
        float4 m4 = mm4(Gb, Ea, r, c0);
        m4.x += (r == c0 + 0) ? 1.f : 0.f; m4.y += (r == c0 + 1) ? 1.f : 0.f;
        m4.z += (r == c0 + 2) ? 1.f : 0.f; m4.w += (r == c0 + 3) ? 1.f : 0.f;
        float4 id4 = make_float4((r == c0 + 0) ? 1.f : 0.f, (r == c0 + 1) ? 1.f : 0.f,
                                 (r == c0 + 2) ? 1.f : 0.f, (r == c0 + 3) ? 1.f : 0.f);
        *(float4*)&Aug[r][c0] = m4;
        *(float4*)&Msv[r][c0] = m4;
        *(float4*)&Aug[r][36 + c0] = id4;
    }
    __syncthreads();
    inv32_256(tid, Aug, Msv, T4);
    {
        float4 t1 = mm4K(Ea, Aug, r, c0);
        float4 t4 = mmK4(Aug, Gb, r, c0);
        float4 t3 = mm4R(Fb, Aug, r, c0);
        *(float4*)&T1[r][c0] = t1; *(float4*)&T4[r][c0] = t4; *(float4*)&T3[r][c0] = t3;
    }
    __syncthreads();
    {
        float4 bt = mm4(Fb, T1, r, c0);
        float4 t5 = mm4(T3, Fa, r, c0);
        float4 fav = *(const float4*)&Fa[r][c0];
        float4 fbv = *(const float4*)&Fb[r][c0];
        *(float4*)&Aug[r][36 + c0] = bt; *(float4*)&T5[r][c0] = t5;
        Ea[c0 + 0][r] = fav.x; Ea[c0 + 1][r] = fav.y;
        Ea[c0 + 2][r] = fav.z; Ea[c0 + 3][r] = fav.w;
        Gb[c0 + 0][r] = fbv.x; Gb[c0 + 1][r] = fbv.y;
        Gb[c0 + 2][r] = fbv.z; Gb[c0 + 3][r] = fbv.w;
    }
    __syncthreads();
    {
        float4 ev = *(const float4*)&Eb[r][c0];
        float4 acc = f4z();
#pragma unroll
        for (int k = 0; k < 32; ++k) acc = f4madd(Aug[r][36 + k], *(const float4*)&Gb[k][c0], acc);
        ev.x += acc.x; ev.y += acc.y; ev.z += acc.z; ev.w += acc.w;
        float4 t1n = mm4(Ea, T4, r, c0);
        *(float4*)&Msv[r][c0] = ev;
        *(float4*)&T1[r][c0] = t1n;
    }
    __syncthreads();
    {
        float4 g4 = mm4(T1, Fa, r, c0);
        float4 ga = *(const float4*)&Ga[r][c0];
        g4.x += ga.x; g4.y += ga.y; g4.z += ga.z; g4.w += ga.w;
        *(float4*)&T3[r][c0] = g4;
    }
    __syncthreads();
}

__device__ __forceinline__ void load_el256(const float* g, int tid,
    float (*E)[36], float (*F)[36], float (*G)[36]) {
    const int r = tid >> 3, c0 = (tid & 7) * 4;
    *(float4*)&E[r][c0] = *(const float4*)&g[tid * 4];
    *(float4*)&F[r][c0] = *(const float4*)&g[1024 + tid * 4];
    *(float4*)&G[r][c0] = *(const float4*)&g[2048 + tid * 4];
}

// symmetrizing copy (E,G sym; F plain). Ends barrier'd.
__device__ void copy_sym(int tid, const float (*sE)[36], const float (*sF)[36],
    const float (*sG)[36], float (*dE)[36], float (*dF)[36], float (*dG)[36]) {
    const int r = tid >> 3, c0 = (tid & 7) * 4;
    float4 e, g;
    e.x = 0.5f * (sE[r][c0 + 0] + sE[c0 + 0][r]); e.y = 0.5f * (sE[r][c0 + 1] + sE[c0 + 1][r]);
    e.z = 0.5f * (sE[r][c0 + 2] + sE[c0 + 2][r]); e.w = 0.5f * (sE[r][c0 + 3] + sE[c0 + 3][r]);
    float4 f = *(const float4*)&sF[r][c0];
    g.x = 0.5f * (sG[r][c0 + 0] + sG[c0 + 0][r]); g.y = 0.5f * (sG[r][c0 + 1] + sG[c0 + 1][r]);
    g.z = 0.5f * (sG[r][c0 + 2] + sG[c0 + 2][r]); g.w = 0.5f * (sG[r][c0 + 3] + sG[c0 + 3][r]);
    __syncthreads();
    *(float4*)&dE[r][c0] = e; *(float4*)&dF[r][c0] = f; *(float4*)&dG[r][c0] = g;
    __syncthreads();
}
__device__ void copy_plain(int tid, const float (*sE)[36], const float (*sF)[36],
    const float (*sG)[36], float (*dE)[36], float (*dF)[36], float (*dG)[36]) {
    const int r = tid >> 3, c0 = (tid & 7) * 4;
    float4 e = *(const float4*)&sE[r][c0];
    float4 f = *(const float4*)&sF[r][c0];
    float4 g = *(const float4*)&sG[r][c0];
    __syncthreads();
    *(float4*)&dE[r][c0] = e; *(float4*)&dF[r][c0] = f; *(float4*)&dG[r][c0] = g;
    __syncthreads();
}

#define COMPOSE_SHARED \
    __shared__ float Ea[32][36], Fa[32][36], Ga[32][36]; \
    __shared__ float Eb[32][36], Fb[32][36], Gb[32][36]; \
    __shared__ float Msv[32][36], T1[32][36], T3[32][36], T4[32][36], T5[32][36]; \
    __shared__ float Aug[32][72];

// build base element {E=Q, F=F, G=H^T R^-1 H} into (E,F,G); temps Ht/RHt/Rs/Ri.
__device__ void build_base(int tid, float (*E)[36], float (*F)[36], float (*G)[36],
    float (*Ht)[36], float (*RHt)[36], float (*Rs)[12], float (*Ri)[12],
    const float* __restrict__ Fg, const float* __restrict__ Hg,
    const float* __restrict__ Qg, const float* __restrict__ Rg)
{
    const int r = tid >> 3, c0 = (tid & 7) * 4;
    if (tid < 64) *(float4*)&Ht[tid >> 3][(tid & 7) * 4] = *(const float4*)&Hg[tid * 4];
    if (tid < 64) Rs[tid >> 3][tid & 7] = Rg[tid];
    *(float4*)&E[r][c0] = *(const float4*)&Qg[tid * 4];
    *(float4*)&F[r][c0] = *(const float4*)&Fg[tid * 4];
    __syncthreads();
    inv8_wave(tid, Rs, Ri);
    __syncthreads();
    {
        int m = tid >> 5, jj = tid & 31;
        float s = 0.f;
#pragma unroll
        for (int n = 0; n < 8; ++n) s += Ri[m][n] * Ht[n][jj];
        RHt[m][jj] = s;
    }
    __syncthreads();
    {
        float4 acc = f4z();
#pragma unroll
        for (int m = 0; m < 8; ++m) acc = f4madd(Ht[m][r], *(const float4*)&RHt[m][c0], acc);
        *(float4*)&G[r][c0] = acc;
    }
    __syncthreads();
}

// ---------------------------------------------------------------------------
// POW (30 independent blocks): block j<16 -> X^(j+1); block 16+k -> Y^(k+2)
// = base^(16(k+2)). Left-to-right binary powering fully in-block.
// ---------------------------------------------------------------------------
__global__ __launch_bounds__(256) void kf_pow(
    const float* __restrict__ Fg, const float* __restrict__ Hg,
    const float* __restrict__ Qg, const float* __restrict__ Rg,
    float* __restrict__ xt, float* __restrict__ yt)
{
    COMPOSE_SHARED
    __shared__ float Rs[8][12], Sis[8][12];
    const int tid = threadIdx.x, b = blockIdx.x;
    const int r = tid >> 3, c0 = (tid & 7) * 4;

    const int n = (b < 16) ? (b + 1) : 16 * (b - 14);   // exponent

    // acc = base  (result position: Msv,T5,T3; temps T1,T4 free)
    build_base(tid, Msv, T5, T3, T1, T4, Rs, Sis, Fg, Hg, Qg, Rg);

    const int msb = 31 - __clz(n);
    for (int k = msb - 1; k >= 0; --k) {
        // acc = acc^2
        copy_sym(tid, Msv, T5, T3, Ea, Fa, Ga);
        copy_plain(tid, Ea, Fa, Ga, Eb, Fb, Gb);
        compose256(tid, Ea, Fa, Ga, Eb, Fb, Gb, Msv, T1, T3, T4, T5, Aug);
        if ((n >> k) & 1) {
            // acc = acc o base (commutes: powers of one generator)
            copy_sym(tid, Msv, T5, T3, Eb, Fb, Gb);
            build_base(tid, Ea, Fa, Ga, T1, T4, Rs, Sis, Fg, Hg, Qg, Rg);
            compose256(tid, Ea, Fa, Ga, Eb, Fb, Gb, Msv, T1, T3, T4, T5, Aug);
        }
    }

    // store symmetrized result
    float* pd = (b < 16) ? (xt + (size_t)b * EL) : (yt + (size_t)(b - 16) * EL);
    float4 e, f, g;
    e.x = 0.5f * (Msv[r][c0 + 0] + Msv[c0 + 0][r]); e.y = 0.5f * (Msv[r][c0 + 1] + Msv[c0 + 1][r]);
    e.z = 0.5f * (Msv[r][c0 + 2] + Msv[c0 + 2][r]); e.w = 0.5f * (Msv[r][c0 + 3] + Msv[c0 + 3][r]);
    f = *(const float4*)&T5[r][c0];
    g.x = 0.5f * (T3[r][c0 + 0] + T3[c0 + 0][r]); g.y = 0.5f * (T3[r][c0 + 1] + T3[c0 + 1][r]);
    g.z = 0.5f * (T3[r][c0 + 2] + T3[c0 + 2][r]); g.w = 0.5f * (T3[r][c0 + 3] + T3[c0 + 3][r]);
    *(float4*)&pd[tid * 4] = e;
    *(float4*)&pd[1024 + tid * 4] = f;
    *(float4*)&pd[2048 + tid * 4] = g;
}

// ---------------------------------------------------------------------------
// FINAL: per t, prefix = Y^q o X^s (one compose), recover P_t, build tables
// ---------------------------------------------------------------------------
__global__ __launch_bounds__(256) void kf_final(
    const float* __restrict__ Fg, const float* __restrict__ Hg,
    const float* __restrict__ Rg, const float* __restrict__ P0,
    const float* __restrict__ xt, const float* __restrict__ yt,
    float* __restrict__ ws)
{
    COMPOSE_SHARED
    __shared__ float Hs[8][36], HPs[8][36], Wms[8][36], Ums[8][36];
    __shared__ float Ss[8][12], Rs[8][12], Sis[8][12];
    const int t = blockIdx.x, tid = threadIdx.x, r = tid >> 3, c0 = (tid & 7) * 4;

    if (t == 0) {
        *(float4*)&Eb[r][c0] = *(const float4*)&P0[tid * 4];
        __syncthreads();
    } else {
        const int i = t - 1, s = (i & 15) + 1, q = i >> 4;
        if (q == 0) {
            load_el256(xt + (size_t)(s - 1) * EL, tid, Msv, T5, T3);
            __syncthreads();
        } else {
            const float* pb2 = (q == 1) ? (xt + 15 * (size_t)EL)
                                        : (yt + (size_t)(q - 2) * EL);
            load_el256(xt + (size_t)(s - 1) * EL, tid, Ea, Fa, Ga);
            load_el256(pb2, tid, Eb, Fb, Gb);
            __syncthreads();
            compose256(tid, Ea, Fa, Ga, Eb, Fb, Gb, Msv, T1, T3, T4, T5, Aug);
        }
        // P_t = E + F*(P0*(I+G*P0)^-1)*F^T   (E=Msv, F=T5, G=T3)
        *(float4*)&Ea[r][c0] = *(const float4*)&P0[tid * 4];
        __syncthreads();
        {
            float4 m4 = mm4(T3, Ea, r, c0);
            m4.x += (r == c0 + 0) ? 1.f : 0.f; m4.y += (r == c0 + 1) ? 1.f : 0.f;
            m4.z += (r == c0 + 2) ? 1.f : 0.f; m4.w += (r == c0 + 3) ? 1.f : 0.f;
            float4 id4 = make_float4((r == c0 + 0) ? 1.f : 0.f, (r == c0 + 1) ? 1.f : 0.f,
                                     (r == c0 + 2) ? 1.f : 0.f, (r == c0 + 3) ? 1.f : 0.f);
            *(float4*)&Aug[r][c0] = m4; *(float4*)&T4[r][c0] = m4;
            *(float4*)&Aug[r][36 + c0] = id4;
        }
        __syncthreads();
        inv32_256(tid, Aug, T4, T1);
        *(float4*)&T1[r][c0] = mm4K(Ea, Aug, r, c0);      // P0*K
        __syncthreads();
        *(float4*)&T4[r][c0] = mm4(T5, T1, r, c0);        // F*(P0K)
        __syncthreads();
        {   // Ga(temp) = Msv + T4*T5^T
            float4 ev = *(const float4*)&Msv[r][c0];
            float s0 = 0, s1 = 0, s2 = 0, s3 = 0;
#pragma unroll
            for (int k = 0; k < 32; ++k) {
                float av = T4[r][k];
                s0 += av * T5[c0 + 0][k]; s1 += av * T5[c0 + 1][k];
                s2 += av * T5[c0 + 2][k]; s3 += av * T5[c0 + 3][k];
            }
            ev.x += s0; ev.y += s1; ev.z += s2; ev.w += s3;
            *(float4*)&Ga[r][c0] = ev;
        }
        __syncthreads();
        {   // Pm symmetrized -> Eb
            float4 e;
            e.x = 0.5f * (Ga[r][c0 + 0] + Ga[c0 + 0][r]); e.y = 0.5f * (Ga[r][c0 + 1] + Ga[c0 + 1][r]);
            e.z = 0.5f * (Ga[r][c0 + 2] + Ga[c0 + 2][r]); e.w = 0.5f * (Ga[r][c0 + 3] + Ga[c0 + 3][r]);
            *(float4*)&Eb[r][c0] = e;
        }
        __syncthreads();
    }

    // ---- tables from Pm = Eb ----
    *(float4*)&Fa[r][c0] = *(const float4*)&Fg[tid * 4];
    if (tid < 64) *(float4*)&Hs[tid >> 3][(tid & 7) * 4] = *(const float4*)&Hg[tid * 4];
    if (tid < 64) Rs[tid >> 3][tid & 7] = Rg[tid];
    __syncthreads();
    {
        int m = tid >> 5, k2 = tid & 31;
        float a = 0.f;
#pragma unroll
        for (int j = 0; j < 32; ++j) a += Hs[m][j] * Eb[j][k2];
        HPs[m][k2] = a;
    }
    __syncthreads();
    {
        int m = tid >> 5, jj = tid & 31;
        float wv = 0.f;
#pragma unroll
        for (int k = 0; k < 32; ++k) wv += HPs[m][k] * Fa[jj][k];
        Wms[m][jj] = wv;
        if (tid < 64) {
            int mm = tid >> 3, n = tid & 7;
            float sv = Rs[mm][n];
#pragma unroll
            for (int k = 0; k < 32; ++k) sv += HPs[mm][k] * Hs[n][k];
            Ss[mm][n] = sv;
            ws[S_OFF + (size_t)t * 64 + tid] = sv;
        }
    }
    __syncthreads();
    inv8_wave(tid, Ss, Sis);
    __syncthreads();
    {
        int m = tid >> 5, s2 = tid & 31;
        float u = 0.f;
#pragma unroll
        for (int n = 0; n < 8; ++n) u += Sis[m][n] * Wms[n][s2];
        Ums[m][s2] = u;
        ws[B_OFF + (size_t)t * 256 + s2 * 8 + m] = u;
    }
    __syncthreads();
    {
        float4 a4 = *(const float4*)&Fa[r][c0];
#pragma unroll
        for (int m = 0; m < 8; ++m) {
            float um = Ums[m][r];
            a4 = f4madd(-um, *(const float4*)&Hs[m][c0], a4);
        }
        ((float4*)(ws + A_OFF))[(size_t)t * 256 + tid] = a4;
    }
}

// ---------------------------------------------------------------------------
// TPRE: per chunk (8 blocks), 32 serial steps: HT_t = H*T_{t0->t}, PHI_c
// ---------------------------------------------------------------------------
__global__ __launch_bounds__(256) void kf_tpre(
    const float* __restrict__ Hg, const float* __restrict__ ws,
    float* __restrict__ ht, float* __restrict__ phi)
{
    __shared__ float Ta[32][36], Tb[32][36], As[32][36], Hs[8][36];
    const int cc = blockIdx.x, tid = threadIdx.x, r = tid >> 3, c0 = (tid & 7) * 4;
    const int t0 = CH * cc;
    const float4* A4 = (const float4*)(ws + A_OFF);

    {
        float4 id4 = make_float4((r == c0 + 0) ? 1.f : 0.f, (r == c0 + 1) ? 1.f : 0.f,
                                 (r == c0 + 2) ? 1.f : 0.f, (r == c0 + 3) ? 1.f : 0.f);
        *(float4*)&Ta[r][c0] = id4;
    }
    if (tid < 64) *(float4*)&Hs[tid >> 3][(tid & 7) * 4] = *(const float4*)&Hg[tid * 4];
    ht[(size_t)t0 * 256 + tid] = Hg[tid];
    *(float4*)&As[r][c0] = A4[(size_t)t0 * 256 + tid];
    __syncthreads();

    float (*cur)[36] = Ta, (*nxt)[36] = Tb;
    for (int k = 1; k <= CH; ++k) {
        *(float4*)&nxt[r][c0] = mm4(As, cur, r, c0);
        __syncthreads();
        if (k < CH) {
            int m = tid >> 5, s2 = tid & 31;
            float h = 0.f;
#pragma unroll
            for (int j = 0; j < 32; ++j) h += Hs[m][j] * nxt[j][s2];
            ht[(size_t)(t0 + k) * 256 + tid] = h;
            *(float4*)&As[r][c0] = A4[(size_t)(t0 + k) * 256 + tid];
        } else {
            ((float4*)phi)[(size_t)cc * 256 + tid] = *(const float4*)&nxt[r][c0];
        }
        __syncthreads();
        float (*tmp)[36] = cur; cur = nxt; nxt = tmp;
    }
}

// ---------------------------------------------------------------------------
// M1: one-wave blocks; A_t/B_t/H in registers, m in LDS; zero barriers.
// ---------------------------------------------------------------------------
__global__ __launch_bounds__(64) void kf_m1(
    const float* __restrict__ obs, const float* __restrict__ Hg,
    const float* __restrict__ ws, float* __restrict__ mend,
    float* __restrict__ means)
{
    __shared__ float mc[8][36];
    __shared__ float us[8][12];
    const int lane = threadIdx.x;
    const int rA = lane >> 1, hA = lane & 1;
    const int rH = lane >> 3, cH = lane & 7;
    const int cc = blockIdx.x >> 8;
    const int gb = (blockIdx.x & 255) * 8;
    const int t0 = cc * CH;
    const float4* A4 = (const float4*)(ws + A_OFF);
    const float4* B4 = (const float4*)(ws + B_OFF);
    const float4* obs4 = (const float4*)obs;

    const float4 h4 = *(const float4*)&Hg[rH * 32 + cH * 4];

    {
        float* mf = &mc[0][0];
        for (int i = lane; i < 8 * 36; i += 64) mf[i] = 0.f;
    }

    float4 an0 = A4[(size_t)t0 * 256 + lane * 4 + 0];
    float4 an1 = A4[(size_t)t0 * 256 + lane * 4 + 1];
    float4 an2 = A4[(size_t)t0 * 256 + lane * 4 + 2];
    float4 an3 = A4[(size_t)t0 * 256 + lane * 4 + 3];
    float4 bn  = B4[(size_t)t0 * 64 + lane];
    float4 un = f4z();
    if (lane < 16) un = obs4[((size_t)(gb + (lane >> 1)) * 256 + t0) * 2 + (lane & 1)];

    for (int k = 0; k < CH; ++k) {
        const int t = t0 + k;
        const float4 a0 = an0, a1 = an1, a2 = an2, a3 = an3, bb = bn;
        if (lane < 16) *(float4*)&us[lane >> 1][(lane & 1) * 4] = un;
        if (k < CH - 1) {
            an0 = A4[(size_t)(t + 1) * 256 + lane * 4 + 0];
            an1 = A4[(size_t)(t + 1) * 256 + lane * 4 + 1];
            an2 = A4[(size_t)(t + 1) * 256 + lane * 4 + 2];
            an3 = A4[(size_t)(t + 1) * 256 + lane * 4 + 3];
            bn  = B4[(size_t)(t + 1) * 64 + lane];
            if (lane < 16) un = obs4[((size_t)(gb + (lane >> 1)) * 256 + t + 1) * 2 + (lane & 1)];
        }
#pragma unroll 1
        for (int gl = 0; gl < 8; ++gl) {
            float4 mh = *(const float4*)&mc[gl][cH * 4];
            float hp = dot4(h4, mh);
            hp += __shfl_xor(hp, 1);
            hp += __shfl_xor(hp, 2);
            hp += __shfl_xor(hp, 4);
            float4 m0v = *(const float4*)&mc[gl][hA * 16 + 0];
            float4 m1v = *(const float4*)&mc[gl][hA * 16 + 4];
            float4 m2v = *(const float4*)&mc[gl][hA * 16 + 8];
            float4 m3v = *(const float4*)&mc[gl][hA * 16 + 12];
            float d = dot4(a0, m0v) + dot4(a1, m1v) + dot4(a2, m2v) + dot4(a3, m3v);
            float4 u4 = *(const float4*)&us[gl][hA * 4];
            d += dot4(bb, u4);
            d += __shfl_xor(d, 1);
            if ((lane & 7) == 0) means[((size_t)(gb + gl) * 256 + t) * 8 + rH] = hp;
            if (hA == 0) mc[gl][rA] = d;
        }
    }
#pragma unroll 1
    for (int gl = 0; gl < 8; ++gl)
        if (hA == 0) mend[((size_t)(gb + gl) * 8 + cc) * 32 + rA] = mc[gl][rA];
}

// ---------------------------------------------------------------------------
// M2: one g per block — chunk prefix (wave 0) + means correction + covs
// ---------------------------------------------------------------------------
__global__ __launch_bounds__(256) void kf_m2(
    const float* __restrict__ m0, const float* __restrict__ ws,
    const float* __restrict__ ht, const float* __restrict__ phi,
    const float* __restrict__ mend, float* __restrict__ out,
    unsigned long long guard4)
{
    __shared__ float mst[256];
    const int tid = threadIdx.x;
    const size_t g = blockIdx.x;

    if (tid < 32) {
        const int s = tid;
        const float4* PHI4 = (const float4*)phi;
        float msr = m0[g * 32 + s];
        for (int cc = 0; cc < C_N; ++cc) {
            mst[cc * 32 + s] = msr;
            if (cc < C_N - 1) {
                float nv = mend[(g * 8 + cc) * 32 + s];
#pragma unroll
                for (int q4 = 0; q4 < 8; ++q4) {
                    float4 p = PHI4[cc * 256 + s * 8 + q4];
                    nv += p.x * __shfl(msr, 4 * q4 + 0, 32) + p.y * __shfl(msr, 4 * q4 + 1, 32)
                        + p.z * __shfl(msr, 4 * q4 + 2, 32) + p.w * __shfl(msr, 4 * q4 + 3, 32);
                }
                msr = nv;
            }
        }
    }
    __syncthreads();

    const float4* HT4 = (const float4*)ht;
#pragma unroll
    for (int j = 0; j < 8; ++j) {
        const int idx = tid + 256 * j;            // = t*8 + m
        const int t = idx >> 3, m = idx & 7, cc = t >> 5;
        float corr = 0.f;
#pragma unroll
        for (int q4 = 0; q4 < 8; ++q4) {
            float4 h = HT4[(size_t)t * 64 + m * 8 + q4];
            float4 mm = *(const float4*)&mst[cc * 32 + 4 * q4];
            corr += dot4(h, mm);
        }
        out[g * 2048 + idx] += corr;
    }

    const float4* S4 = (const float4*)(ws + S_OFF);
    float4* covs4 = (float4*)out + COVS4_BASE;
#pragma unroll
    for (int k = 0; k < 16; ++k) {
        const size_t i = (size_t)tid + 256 * k;
        const size_t rel = g * 4096 + i;
        if (rel < guard4) covs4[rel] = S4[i];
    }
}

// ---------------------------------------------------------------------------
// CLEAN (fallback only): fill the covs span that was used as scratch
// ---------------------------------------------------------------------------
__global__ void kf_clean(const float* __restrict__ ws, float* __restrict__ out)
{
    float4* out4 = (float4*)out;
    const float4* S4 = (const float4*)(ws + S_OFF);
    const size_t start = COVS4_BASE + FB_GUARD4;
    const size_t end = OUT_TOTAL / 4;
    size_t i = start + (size_t)blockIdx.x * blockDim.x + threadIdx.x;
    const size_t stride = (size_t)gridDim.x * blockDim.x;
    for (; i < end; i += stride) {
        size_t rel = i - COVS4_BASE;
        out4[i] = S4[rel & 4095];
    }
}

extern "C" void kernel_launch(void* const* d_in, const int* in_sizes, int n_in,
                              void* d_out, int out_size, void* d_ws, size_t ws_size,
                              hipStream_t stream) {
    const float* obs = (const float*)d_in[0];
    const float* F   = (const float*)d_in[1];
    const float* H   = (const float*)d_in[2];
    const float* Q   = (const float*)d_in[3];
    const float* R   = (const float*)d_in[4];
    const float* m0  = (const float*)d_in[5];
    const float* P0  = (const float*)d_in[6];
    float* out = (float*)d_out;
    float* ws  = (float*)d_ws;

    const bool use_ws = (ws_size >= WS_NEED_BYTES);
    float *xt, *yt, *ht, *phi, *mend;
    unsigned long long guard4;
    if (use_ws) {
        xt = ws + WS_XT; yt = ws + WS_YT; ht = ws + WS_HT;
        phi = ws + WS_PHI; mend = ws + WS_MEND;
        guard4 = 4096ull * (unsigned long long)G_N;   // no clipping
    } else {
        xt = out + XT_OFF; yt = out + YT_OFF; ht = out + HT_OFF;
        phi = out + PHI_OFF; mend = out + MEND_OFF;
        guard4 = FB_GUARD4;
    }

    kf_pow  <<<30,   256, 0, stream>>>(F, H, Q, R, xt, yt);
    kf_final<<<256,  256, 0, stream>>>(F, H, R, P0, xt, yt, ws);
    kf_tpre <<<8,    256, 0, stream>>>(H, ws, ht, phi);
    kf_m1   <<<2048, 64,  0, stream>>>(obs, H, ws, mend, out);
    kf_m2   <<<2048, 256, 0, stream>>>(m0, ws, ht, phi, mend, out, guard4);
    if (!use_ws) kf_clean<<<512, 256, 0, stream>>>(ws, out);
}